// Round 2
// 892.817 us; speedup vs baseline: 1.0192x; 1.0192x over previous
//
#include <hip/hip_runtime.h>
#include <math.h>

// Problem constants (B=16384 rows, C=8192 classes), M=2.0, N=0.2, EPS=1e-5
#define BROWS 16384
#define CCOLS 8192
#define MARGIN_DIV 2.00001f
#define MARGIN_SHIFT 0.2f

typedef float vfloat4 __attribute__((ext_vector_type(4)));

// ---------------- setup kernels (tiny) ----------------

__global__ void k0_init(int* __restrict__ first_occ, int* __restrict__ cnt,
                        int* __restrict__ ctr) {
    int idx = blockIdx.x * 256 + threadIdx.x;
    if (idx < CCOLS) {
        first_occ[idx] = 0x7fffffff;
        cnt[idx] = 0;
        ctr[idx] = 0;
    }
}

__global__ void k1_hist(const int* __restrict__ labels, int* __restrict__ first_occ,
                        int* __restrict__ cnt) {
    int r = blockIdx.x * 256 + threadIdx.x;
    if (r < BROWS) {
        int lab = labels[r];
        atomicMin(&first_occ[lab], r);
        atomicAdd(&cnt[lab], 1);
    }
}

// fused grpcnt + exclusive scan over BROWS rows.
// grpcnt[p] = cnt[label[p]] if p is the first occurrence of its label else 0
// (computed inline -- no global round-trip). 1024 threads x 16 elems.
__global__ __launch_bounds__(1024) void k3_scan(const int* __restrict__ labels,
                                                const int* __restrict__ first_occ,
                                                const int* __restrict__ cnt,
                                                int* __restrict__ scanarr) {
    __shared__ int sums[1024];
    int t = threadIdx.x;
    int base = t * 16;
    int g[16];
    int local = 0;
    #pragma unroll
    for (int j = 0; j < 16; j++) {
        int p = base + j;
        int lab = labels[p];
        int gg = (first_occ[lab] == p) ? cnt[lab] : 0;
        g[j] = gg;
        local += gg;
    }
    sums[t] = local;
    __syncthreads();
    for (int off = 1; off < 1024; off <<= 1) {
        int v = (t >= off) ? sums[t - off] : 0;
        __syncthreads();
        sums[t] += v;
        __syncthreads();
    }
    int run = sums[t] - local;  // exclusive prefix for this chunk
    #pragma unroll
    for (int j = 0; j < 16; j++) {
        scanarr[base + j] = run;
        run += g[j];
    }
}

// scatter each row into its label's bucket (unordered slots)
__global__ void k4_bucket(const int* __restrict__ labels, const int* __restrict__ first_occ,
                          const int* __restrict__ scanarr, int* __restrict__ ctr,
                          int* __restrict__ bucket) {
    int r = blockIdx.x * 256 + threadIdx.x;
    if (r < BROWS) {
        int lab = labels[r];
        int slot = atomicAdd(&ctr[lab], 1);
        int base = scanarr[first_occ[lab]];
        bucket[base + slot] = r;
    }
}

// sort each tiny bucket ascending (restores stability), then emit the
// inverse permutation: invperm[input_row] = output_row.
__global__ void k5_sortgroups(const int* __restrict__ first_occ, const int* __restrict__ cnt,
                              const int* __restrict__ scanarr, int* __restrict__ bucket,
                              int* __restrict__ invperm) {
    int c = blockIdx.x * 256 + threadIdx.x;
    if (c < CCOLS) {
        int n = cnt[c];
        if (n > 0) {
            int base = scanarr[first_occ[c]];
            for (int a = 1; a < n; a++) {
                int key = bucket[base + a];
                int b = a - 1;
                while (b >= 0 && bucket[base + b] > key) {
                    bucket[base + b + 1] = bucket[base + b];
                    b--;
                }
                bucket[base + b + 1] = key;
            }
            for (int s = 0; s < n; s++) invperm[bucket[base + s]] = base + s;
        }
    }
}

// ---------------- main fused kernel ----------------
// block r: read INPUT row r (sequential streaming reads), apply margin at label
// col, write output row invperm[r] (scattered 32KB streams -- fire and forget),
// compute logsumexp and partial loss. Stores issued in pass 1 (margined values
// don't depend on the max) so the write stream overlaps the load phase.
// Reduction order identical to the previously-verified version (bit-stable loss).
__global__ __launch_bounds__(256) void k6_main(const float* __restrict__ logits,
                                               const int* __restrict__ labels,
                                               const int* __restrict__ invperm,
                                               float* __restrict__ out,
                                               float* __restrict__ partials) {
    int r = blockIdx.x;          // input row
    int i = invperm[r];          // output row
    int lab = labels[r];
    const vfloat4* src = (const vfloat4*)(logits + (size_t)r * CCOLS);
    vfloat4* dst = (vfloat4*)(out + (size_t)i * CCOLS);
    int t = threadIdx.x;

    vfloat4 v[8];
    float tmax = -INFINITY;
    float tval = 0.0f;
    bool havet = false;

    #pragma unroll
    for (int k = 0; k < 8; k++) {
        int f4 = t + k * 256;
        vfloat4 x = __builtin_nontemporal_load(src + f4);
        int col = f4 * 4;
        if (col <= lab && lab < col + 4) {
            int e = lab - col;
            float vv = (e == 0) ? x.x : (e == 1) ? x.y : (e == 2) ? x.z : x.w;
            vv = (vv > 0.0f) ? (vv / MARGIN_DIV - MARGIN_SHIFT)
                             : (vv * MARGIN_DIV - MARGIN_SHIFT);
            if (e == 0) x.x = vv; else if (e == 1) x.y = vv;
            else if (e == 2) x.z = vv; else x.w = vv;
            tval = vv;
            havet = true;
        }
        __builtin_nontemporal_store(x, dst + f4);
        v[k] = x;
        tmax = fmaxf(tmax, fmaxf(fmaxf(x.x, x.y), fmaxf(x.z, x.w)));
    }

    __shared__ float smax[4], ssum[4], stval;
    int wave = t >> 6, lane = t & 63;
    #pragma unroll
    for (int off = 32; off > 0; off >>= 1)
        tmax = fmaxf(tmax, __shfl_down(tmax, off, 64));
    if (lane == 0) smax[wave] = tmax;
    if (havet) stval = tval;
    __syncthreads();
    float rmax = fmaxf(fmaxf(smax[0], smax[1]), fmaxf(smax[2], smax[3]));

    float tsum = 0.0f;
    #pragma unroll
    for (int k = 0; k < 8; k++) {
        vfloat4 x = v[k];
        tsum += __expf(x.x - rmax) + __expf(x.y - rmax) +
                __expf(x.z - rmax) + __expf(x.w - rmax);
    }
    #pragma unroll
    for (int off = 32; off > 0; off >>= 1)
        tsum += __shfl_down(tsum, off, 64);
    if (lane == 0) ssum[wave] = tsum;
    __syncthreads();

    if (t == 0) {
        float s = ssum[0] + ssum[1] + ssum[2] + ssum[3];
        partials[i] = (rmax + __logf(s)) - stval;         // lse - target
        out[(size_t)BROWS * CCOLS + i] = (float)lab;      // permuted label output
    }
}

// final loss: mean(partials)  (same order as the verified version)
__global__ void k7_loss(const float* __restrict__ partials, float* __restrict__ out_loss) {
    __shared__ float s[256];
    int t = threadIdx.x;
    float a = 0.0f;
    for (int j = t; j < BROWS; j += 256) a += partials[j];
    s[t] = a;
    __syncthreads();
    for (int off = 128; off > 0; off >>= 1) {
        if (t < off) s[t] += s[t + off];
        __syncthreads();
    }
    if (t == 0) *out_loss = s[0] / (float)BROWS;
}

extern "C" void kernel_launch(void* const* d_in, const int* in_sizes, int n_in,
                              void* d_out, int out_size, void* d_ws, size_t ws_size,
                              hipStream_t stream) {
    const float* logits = (const float*)d_in[0];
    const int* labels = (const int*)d_in[1];
    float* out = (float*)d_out;

    // workspace layout
    int* first_occ = (int*)d_ws;              // C
    int* cnt = first_occ + CCOLS;             // C
    int* ctr = cnt + CCOLS;                   // C
    int* scanarr = ctr + CCOLS;               // B
    int* bucket = scanarr + BROWS;            // B
    int* invperm = bucket + BROWS;            // B
    float* partials = (float*)(invperm + BROWS); // B

    k0_init<<<CCOLS / 256, 256, 0, stream>>>(first_occ, cnt, ctr);
    k1_hist<<<BROWS / 256, 256, 0, stream>>>(labels, first_occ, cnt);
    k3_scan<<<1, 1024, 0, stream>>>(labels, first_occ, cnt, scanarr);
    k4_bucket<<<BROWS / 256, 256, 0, stream>>>(labels, first_occ, scanarr, ctr, bucket);
    k5_sortgroups<<<CCOLS / 256, 256, 0, stream>>>(first_occ, cnt, scanarr, bucket, invperm);
    k6_main<<<BROWS, 256, 0, stream>>>(logits, labels, invperm, out, partials);
    k7_loss<<<1, 256, 0, stream>>>(partials, out + (size_t)BROWS * CCOLS + BROWS);
}